// Round 1
// baseline (153.362 us; speedup 1.0000x reference)
//
#include <hip/hip_runtime.h>
#include <stdint.h>

#define LOG2E 1.44269504088896340736f

using bf16x8 = __attribute__((ext_vector_type(8))) short;  // 8 bf16 (4 VGPRs)
using f32x4  = __attribute__((ext_vector_type(4))) float;

__device__ __forceinline__ ushort f2bf(float f) {
  union { float f; uint32_t u; } v; v.f = f;
  uint32_t u = v.u;
  u += 0x7FFFu + ((u >> 16) & 1u);   // RNE
  return (ushort)(u >> 16);
}
__device__ __forceinline__ float bf2f(ushort b) {
  union { uint32_t u; float f; } v; v.u = ((uint32_t)b) << 16;
  return v.f;
}

__device__ __forceinline__ void load_lds16(const void* g, void* l) {
  __builtin_amdgcn_global_load_lds(
      (const __attribute__((address_space(1))) void*)g,
      (__attribute__((address_space(3))) void*)l, 16, 0, 0);
}

// out[row] = dot(mat[row, 0:512], vec[0:512]); 4 rows per 256-thread block
__global__ void rowdot(const float* __restrict__ mat, const float* __restrict__ vec,
                       float* __restrict__ out) {
  int w = threadIdx.x >> 6, l = threadIdx.x & 63;
  int row = blockIdx.x * 4 + w;
  const float4* mp = (const float4*)(mat + row * 512 + l * 8);
  const float4* vp = (const float4*)(vec + l * 8);
  float4 a0 = mp[0], a1 = mp[1];
  float4 b0 = vp[0], b1 = vp[1];
  float d = a0.x * b0.x + a0.y * b0.y + a0.z * b0.z + a0.w * b0.w
          + a1.x * b1.x + a1.y * b1.y + a1.z * b1.z + a1.w * b1.w;
#pragma unroll
  for (int o = 32; o > 0; o >>= 1) d += __shfl_xor(d, o, 64);
  if (l == 0) out[row] = d;
}

__global__ void reduce_max(const float* __restrict__ v, float* __restrict__ outmax) {
  __shared__ float red[4];
  int t = threadIdx.x;
  float m = -3.0e38f;
  for (int j = t; j < 8192; j += 256) m = fmaxf(m, v[j]);
#pragma unroll
  for (int o = 32; o > 0; o >>= 1) m = fmaxf(m, __shfl_xor(m, o, 64));
  if ((t & 63) == 0) red[t >> 6] = m;
  __syncthreads();
  if (t == 0) outmax[0] = fmaxf(fmaxf(red[0], red[1]), fmaxf(red[2], red[3]));
}

// float4 -> ushort4 bf16 convert (n/4 threads)
__global__ void cvt4_bf16(const float* __restrict__ in, ushort* __restrict__ out) {
  int idx = blockIdx.x * 256 + threadIdx.x;
  float4 v = ((const float4*)in)[idx];
  ushort4 o; o.x = f2bf(v.x); o.y = f2bf(v.y); o.z = f2bf(v.z); o.w = f2bf(v.w);
  ((ushort4*)out)[idx] = o;
}

// wT_bf[f][c] = bf16(weight[c][f]); 512x512
__global__ void transpose_w(const float* __restrict__ w, ushort* __restrict__ wT) {
  __shared__ float tile[32][33];
  int t = threadIdx.x; int tx = t & 31, ty = t >> 5;  // ty 0..7
  int cb = (blockIdx.x & 15) * 32, fb = (blockIdx.x >> 4) * 32;
#pragma unroll
  for (int k = 0; k < 4; ++k) tile[ty + k * 8][tx] = w[(cb + ty + k * 8) * 512 + fb + tx];
  __syncthreads();
#pragma unroll
  for (int k = 0; k < 4; ++k) wT[(fb + ty + k * 8) * 512 + cb + tx] = f2bf(tile[tx][ty + k * 8]);
}

// WhmT[f][j] = sum_c neigh_bf[j][c] * wT_bf[f][c]   (bf16 out, transposed store)
// grid 256 = (8192/128) x (512/128); 256 threads = 4 waves (2x2), 64x64 per wave
__global__ __launch_bounds__(256, 4) void gemm_whmT(const ushort* __restrict__ A,
                                                    const ushort* __restrict__ B,
                                                    ushort* __restrict__ WhmT) {
  __shared__ ushort At[128 * 32];
  __shared__ ushort Bt2[128 * 32];
  int t = threadIdx.x;
  int j0 = (blockIdx.x >> 2) * 128, f0 = (blockIdx.x & 3) * 128;
  int w = t >> 6, l = t & 63, wr = w >> 1, wc = w & 1;
  f32x4 acc[4][4] = {};
  for (int it = 0; it < 16; ++it) {
    int k0 = it * 32;
#pragma unroll
    for (int c = 0; c < 2; ++c) {
      int u = c * 256 + t; int rr = u >> 2, p = u & 3;
      int sg = p ^ ((rr >> 1) & 3);
      load_lds16(A + (j0 + rr) * 512 + k0 + sg * 8, At + (c * 256 + (t & ~63)) * 8);
      load_lds16(B + (f0 + rr) * 512 + k0 + sg * 8, Bt2 + (c * 256 + (t & ~63)) * 8);
    }
    __syncthreads();
    bf16x8 af[4], bfr[4];
#pragma unroll
    for (int m = 0; m < 4; ++m) {
      int rr = wr * 64 + m * 16 + (l & 15);
      int q = (l >> 4) ^ ((rr >> 1) & 3);
      af[m] = *(const bf16x8*)(At + rr * 32 + q * 8);
    }
#pragma unroll
    for (int n = 0; n < 4; ++n) {
      int rb = wc * 64 + n * 16 + (l & 15);
      int q = (l >> 4) ^ ((rb >> 1) & 3);
      bfr[n] = *(const bf16x8*)(Bt2 + rb * 32 + q * 8);
    }
#pragma unroll
    for (int m = 0; m < 4; ++m)
#pragma unroll
      for (int n = 0; n < 4; ++n)
        acc[m][n] = __builtin_amdgcn_mfma_f32_16x16x32_bf16(af[m], bfr[n], acc[m][n], 0, 0, 0);
    __syncthreads();
  }
#pragma unroll
  for (int m = 0; m < 4; ++m)
#pragma unroll
    for (int n = 0; n < 4; ++n) {
      int j = j0 + wr * 64 + m * 16 + (l >> 4) * 4;
      int f = f0 + wc * 64 + n * 16 + (l & 15);
      ushort4 o;
      o.x = f2bf(acc[m][n][0]); o.y = f2bf(acc[m][n][1]);
      o.z = f2bf(acc[m][n][2]); o.w = f2bf(acc[m][n][3]);
      *(ushort4*)(WhmT + f * 8192 + j) = o;
    }
}

// Main fused kernel: num[s][i][f] = sum_{j in ksplit s} P[i][j]*Whm[j][f]; den[s][i] = sum_j P[i][j]
// P[i][j] = mask ? exp(lrelu(sn[i]+sm[j]) - m_i) : 0,  m_i = lrelu(sn[i]+Smax)
// grid 256 = 64 row-blocks (BM=64) x 4 ksplits (2048 j each); 512 threads = 8 waves, BN=512
__global__ __launch_bounds__(512, 4) void attn_main(
    const ushort* __restrict__ WhmT, const int* __restrict__ mask,
    const float* __restrict__ s_n, const float* __restrict__ s_m,
    const float* __restrict__ smaxp, float* __restrict__ num, float* __restrict__ den) {
  __shared__ ushort Bt[512 * 32];  // Whm^T tile [f][32j], xor-swizzled
  __shared__ ushort Pt[64 * 32];   // P tile [i][32j], xor-swizzled
  int t = threadIdx.x;
  int rblk = blockIdx.x >> 2, s = blockIdx.x & 3;
  int i0 = rblk * 64;
  int kb = s * 2048;
  int i_loc = t >> 3, jt = t & 7;
  int w = t >> 6, l = t & 63;
  float sn = s_n[i0 + i_loc];
  float smx = smaxp[0];
  float mz = sn + smx;
  float m_i = mz > 0.f ? mz : 0.2f * mz;
  float miL = m_i * LOG2E;
  float dacc = 0.f;
  f32x4 acc[4][4] = {};
  int psP = (jt >> 1) ^ ((i_loc >> 1) & 3);
  ushort* pdst = Pt + i_loc * 32 + psP * 8 + (jt & 1) * 4;
  const int* mrow = mask + (i0 + i_loc) * 8192 + jt * 4;

  for (int it = 0; it < 64; ++it) {
    int k0 = kb + it * 32;
    // stage B tile: 512 rows x 64B, linear LDS dest + pre-swizzled global source
#pragma unroll
    for (int c = 0; c < 4; ++c) {
      int u = c * 512 + t; int rr = u >> 2, p = u & 3;
      int sg = p ^ ((rr >> 1) & 3);
      load_lds16(WhmT + rr * 8192 + k0 + sg * 8, Bt + (c * 512 + (t & ~63)) * 8);
    }
    // compute P tile: 4 consecutive j per thread
    int4 mk = *(const int4*)(mrow + k0);
    float4 smv = *(const float4*)(s_m + k0 + jt * 4);
    float z0 = sn + smv.x, z1 = sn + smv.y, z2 = sn + smv.z, z3 = sn + smv.w;
    float e0 = (z0 > 0.f ? z0 : 0.2f * z0) * LOG2E - miL;
    float e1 = (z1 > 0.f ? z1 : 0.2f * z1) * LOG2E - miL;
    float e2 = (z2 > 0.f ? z2 : 0.2f * z2) * LOG2E - miL;
    float e3 = (z3 > 0.f ? z3 : 0.2f * z3) * LOG2E - miL;
    float p0 = mk.x > 0 ? exp2f(e0) : 0.f;
    float p1 = mk.y > 0 ? exp2f(e1) : 0.f;
    float p2 = mk.z > 0 ? exp2f(e2) : 0.f;
    float p3 = mk.w > 0 ? exp2f(e3) : 0.f;
    ushort4 pv;
    pv.x = f2bf(p0); pv.y = f2bf(p1); pv.z = f2bf(p2); pv.w = f2bf(p3);
    dacc += bf2f(pv.x) + bf2f(pv.y) + bf2f(pv.z) + bf2f(pv.w);
    *(ushort4*)pdst = pv;
    __syncthreads();
    // MFMA phase
    bf16x8 af[4], bfr[4];
#pragma unroll
    for (int m = 0; m < 4; ++m) {
      int rr2 = m * 16 + (l & 15);
      int q = (l >> 4) ^ ((rr2 >> 1) & 3);
      af[m] = *(const bf16x8*)(Pt + rr2 * 32 + q * 8);
    }
#pragma unroll
    for (int n = 0; n < 4; ++n) {
      int rb2 = w * 64 + n * 16 + (l & 15);
      int q = (l >> 4) ^ ((rb2 >> 1) & 3);
      bfr[n] = *(const bf16x8*)(Bt + rb2 * 32 + q * 8);
    }
#pragma unroll
    for (int m = 0; m < 4; ++m)
#pragma unroll
      for (int n = 0; n < 4; ++n)
        acc[m][n] = __builtin_amdgcn_mfma_f32_16x16x32_bf16(af[m], bfr[n], acc[m][n], 0, 0, 0);
    __syncthreads();
  }
  // denominator: 8 threads per row, all in one wave
  dacc += __shfl_xor(dacc, 4, 64);
  dacc += __shfl_xor(dacc, 2, 64);
  dacc += __shfl_xor(dacc, 1, 64);
  if ((t & 7) == 0) den[s * 4096 + i0 + i_loc] = dacc;
  // partial numerator write (f32)
#pragma unroll
  for (int m = 0; m < 4; ++m)
#pragma unroll
    for (int n = 0; n < 4; ++n) {
      int i = i0 + m * 16 + (l >> 4) * 4;
      int f = w * 64 + n * 16 + (l & 15);
      float* dst = num + (s * 4096 + i) * 512 + f;
      dst[0]       = acc[m][n][0];
      dst[512]     = acc[m][n][1];
      dst[2 * 512] = acc[m][n][2];
      dst[3 * 512] = acc[m][n][3];
    }
}

// out[i][f] = sum_s num[s][i][f] / sum_s den[s][i]
__global__ void reduce_out(const float* __restrict__ num, const float* __restrict__ den,
                           float* __restrict__ out) {
  int idx = blockIdx.x * 256 + threadIdx.x;  // 524288 threads
  int i = idx >> 7, f4 = (idx & 127) * 4;
  float4 a = *(const float4*)(num + (size_t)(0 * 4096 + i) * 512 + f4);
  float4 b = *(const float4*)(num + (size_t)(1 * 4096 + i) * 512 + f4);
  float4 c = *(const float4*)(num + (size_t)(2 * 4096 + i) * 512 + f4);
  float4 d = *(const float4*)(num + (size_t)(3 * 4096 + i) * 512 + f4);
  float dn = den[i] + den[4096 + i] + den[2 * 4096 + i] + den[3 * 4096 + i];
  float inv = 1.f / dn;
  float4 o;
  o.x = (a.x + b.x + c.x + d.x) * inv;
  o.y = (a.y + b.y + c.y + d.y) * inv;
  o.z = (a.z + b.z + c.z + d.z) * inv;
  o.w = (a.w + b.w + c.w + d.w) * inv;
  *(float4*)(out + (size_t)i * 512 + f4) = o;
}

extern "C" void kernel_launch(void* const* d_in, const int* in_sizes, int n_in,
                              void* d_out, int out_size, void* d_ws, size_t ws_size,
                              hipStream_t stream) {
  const float* node   = (const float*)d_in[0];
  const float* neigh  = (const float*)d_in[1];
  const float* weight = (const float*)d_in[2];
  const float* att    = (const float*)d_in[3];
  const int*   mask   = (const int*)d_in[4];
  float* out = (float*)d_out;

  char* ws = (char*)d_ws;
  float* w_a1 = (float*)ws;            // 512
  float* w_a2 = w_a1 + 512;            // 512
  float* s_n  = w_a2 + 512;            // 4096
  float* s_m  = s_n + 4096;            // 8192
  float* smax = s_m + 8192;            // 1
  ushort* neigh_bf = (ushort*)(ws + 64 * 1024);    // 8 MB
  ushort* wT_bf    = neigh_bf + 8192 * 512;        // 0.5 MB
  ushort* WhmT     = wT_bf + 512 * 512;            // 8 MB
  float*  num      = (float*)(WhmT + 512 * 8192);  // 32 MB
  float*  den      = num + 4 * 4096 * 512;         // 64 KB

  rowdot<<<128, 256, 0, stream>>>(weight, att, w_a1);
  rowdot<<<128, 256, 0, stream>>>(weight, att + 512, w_a2);
  rowdot<<<1024, 256, 0, stream>>>(node, w_a1, s_n);
  rowdot<<<2048, 256, 0, stream>>>(neigh, w_a2, s_m);
  reduce_max<<<1, 256, 0, stream>>>(s_m, smax);
  cvt4_bf16<<<4096, 256, 0, stream>>>(neigh, neigh_bf);
  transpose_w<<<256, 256, 0, stream>>>(weight, wT_bf);
  gemm_whmT<<<256, 256, 0, stream>>>(neigh_bf, wT_bf, WhmT);
  attn_main<<<256, 512, 0, stream>>>(WhmT, mask, s_n, s_m, smax, num, den);
  reduce_out<<<2048, 256, 0, stream>>>(num, den, out);
}

// Round 2
// 148.082 us; speedup vs baseline: 1.0357x; 1.0357x over previous
//
#include <hip/hip_runtime.h>
#include <stdint.h>

#define LOG2E 1.44269504088896340736f

using bf16x8 = __attribute__((ext_vector_type(8))) short;  // 8 bf16 (4 VGPRs)
using f32x4  = __attribute__((ext_vector_type(4))) float;

__device__ __forceinline__ ushort f2bf(float f) {
  union { float f; uint32_t u; } v; v.f = f;
  uint32_t u = v.u;
  u += 0x7FFFu + ((u >> 16) & 1u);   // RNE
  return (ushort)(u >> 16);
}
__device__ __forceinline__ float bf2f(ushort b) {
  union { uint32_t u; float f; } v; v.u = ((uint32_t)b) << 16;
  return v.f;
}

__device__ __forceinline__ void load_lds16(const void* g, void* l) {
  __builtin_amdgcn_global_load_lds(
      (const __attribute__((address_space(1))) void*)g,
      (__attribute__((address_space(3))) void*)l, 16, 0, 0);
}

// out[row] = dot(mat[row, 0:512], vec[0:512]); 4 rows per 256-thread block
__global__ void rowdot(const float* __restrict__ mat, const float* __restrict__ vec,
                       float* __restrict__ out) {
  int w = threadIdx.x >> 6, l = threadIdx.x & 63;
  int row = blockIdx.x * 4 + w;
  const float4* mp = (const float4*)(mat + row * 512 + l * 8);
  const float4* vp = (const float4*)(vec + l * 8);
  float4 a0 = mp[0], a1 = mp[1];
  float4 b0 = vp[0], b1 = vp[1];
  float d = a0.x * b0.x + a0.y * b0.y + a0.z * b0.z + a0.w * b0.w
          + a1.x * b1.x + a1.y * b1.y + a1.z * b1.z + a1.w * b1.w;
#pragma unroll
  for (int o = 32; o > 0; o >>= 1) d += __shfl_xor(d, o, 64);
  if (l == 0) out[row] = d;
}

__global__ void reduce_max(const float* __restrict__ v, float* __restrict__ outmax) {
  __shared__ float red[4];
  int t = threadIdx.x;
  float m = -3.0e38f;
  for (int j = t; j < 8192; j += 256) m = fmaxf(m, v[j]);
#pragma unroll
  for (int o = 32; o > 0; o >>= 1) m = fmaxf(m, __shfl_xor(m, o, 64));
  if ((t & 63) == 0) red[t >> 6] = m;
  __syncthreads();
  if (t == 0) outmax[0] = fmaxf(fmaxf(red[0], red[1]), fmaxf(red[2], red[3]));
}

// float4 -> ushort4 bf16 convert (n/4 threads)
__global__ void cvt4_bf16(const float* __restrict__ in, ushort* __restrict__ out) {
  int idx = blockIdx.x * 256 + threadIdx.x;
  float4 v = ((const float4*)in)[idx];
  ushort4 o; o.x = f2bf(v.x); o.y = f2bf(v.y); o.z = f2bf(v.z); o.w = f2bf(v.w);
  ((ushort4*)out)[idx] = o;
}

// wT_bf[f][c] = bf16(weight[c][f]); 512x512
__global__ void transpose_w(const float* __restrict__ w, ushort* __restrict__ wT) {
  __shared__ float tile[32][33];
  int t = threadIdx.x; int tx = t & 31, ty = t >> 5;  // ty 0..7
  int cb = (blockIdx.x & 15) * 32, fb = (blockIdx.x >> 4) * 32;
#pragma unroll
  for (int k = 0; k < 4; ++k) tile[ty + k * 8][tx] = w[(cb + ty + k * 8) * 512 + fb + tx];
  __syncthreads();
#pragma unroll
  for (int k = 0; k < 4; ++k) wT[(fb + ty + k * 8) * 512 + cb + tx] = f2bf(tile[tx][ty + k * 8]);
}

// WhmT[f][j] = sum_c neigh_bf[j][c] * wT_bf[f][c]   (bf16 out, transposed store)
__global__ __launch_bounds__(256, 4) void gemm_whmT(const ushort* __restrict__ A,
                                                    const ushort* __restrict__ B,
                                                    ushort* __restrict__ WhmT) {
  __shared__ ushort At[128 * 32];
  __shared__ ushort Bt2[128 * 32];
  int t = threadIdx.x;
  int j0 = (blockIdx.x >> 2) * 128, f0 = (blockIdx.x & 3) * 128;
  int w = t >> 6, l = t & 63, wr = w >> 1, wc = w & 1;
  f32x4 acc[4][4] = {};
  for (int it = 0; it < 16; ++it) {
    int k0 = it * 32;
#pragma unroll
    for (int c = 0; c < 2; ++c) {
      int u = c * 256 + t; int rr = u >> 2, p = u & 3;
      int sg = p ^ ((rr >> 1) & 3);
      load_lds16(A + (j0 + rr) * 512 + k0 + sg * 8, At + (c * 256 + (t & ~63)) * 8);
      load_lds16(B + (f0 + rr) * 512 + k0 + sg * 8, Bt2 + (c * 256 + (t & ~63)) * 8);
    }
    __syncthreads();
    bf16x8 af[4], bfr[4];
#pragma unroll
    for (int m = 0; m < 4; ++m) {
      int rr = wr * 64 + m * 16 + (l & 15);
      int q = (l >> 4) ^ ((rr >> 1) & 3);
      af[m] = *(const bf16x8*)(At + rr * 32 + q * 8);
    }
#pragma unroll
    for (int n = 0; n < 4; ++n) {
      int rb = wc * 64 + n * 16 + (l & 15);
      int q = (l >> 4) ^ ((rb >> 1) & 3);
      bfr[n] = *(const bf16x8*)(Bt2 + rb * 32 + q * 8);
    }
#pragma unroll
    for (int m = 0; m < 4; ++m)
#pragma unroll
      for (int n = 0; n < 4; ++n)
        acc[m][n] = __builtin_amdgcn_mfma_f32_16x16x32_bf16(af[m], bfr[n], acc[m][n], 0, 0, 0);
    __syncthreads();
  }
#pragma unroll
  for (int m = 0; m < 4; ++m)
#pragma unroll
    for (int n = 0; n < 4; ++n) {
      int j = j0 + wr * 64 + m * 16 + (l >> 4) * 4;
      int f = f0 + wc * 64 + n * 16 + (l & 15);
      ushort4 o;
      o.x = f2bf(acc[m][n][0]); o.y = f2bf(acc[m][n][1]);
      o.z = f2bf(acc[m][n][2]); o.w = f2bf(acc[m][n][3]);
      *(ushort4*)(WhmT + f * 8192 + j) = o;
    }
}

// Main fused kernel, software-pipelined:
//   num[s][i][f] = sum_{j in ksplit s} P[i][j]*Whm[j][f]; den[s][i] = sum_j P[i][j]
//   P[i][j] = mask ? exp(lrelu(sn[i]+sm[j]) - m_i) : 0,  m_i = lrelu(sn[i]+Smax)
// grid 256 = 64 row-blocks (BM=64) x 4 ksplits (2048 j each); 512 threads = 8 waves, BN=512
// B tile double-buffered; STAGE(next) issued right after barrier1 so the 32KB
// transfer overlaps MFMA(cur) + P-compute(next). Single vmcnt(0) drain per iter,
// at a point where the load has had a full iteration to complete.
__global__ __launch_bounds__(512) void attn_main(
    const ushort* __restrict__ WhmT, const int* __restrict__ mask,
    const float* __restrict__ s_n, const float* __restrict__ s_m,
    const float* __restrict__ smaxp, float* __restrict__ num, float* __restrict__ den) {
  __shared__ ushort Bt[2][512 * 32];  // 2 x 32 KB, xor-swizzled [f][32j]
  __shared__ ushort Pt[64 * 32];      // 4 KB, xor-swizzled [i][32j]
  int t = threadIdx.x;
  int rblk = blockIdx.x >> 2, s = blockIdx.x & 3;
  int i0 = rblk * 64;
  int kb = s * 2048;
  int i_loc = t >> 3, jt = t & 7;
  int w = t >> 6, l = t & 63;
  float sn = s_n[i0 + i_loc];
  float smx = smaxp[0];
  float mz = sn + smx;
  float m_i = mz > 0.f ? mz : 0.2f * mz;
  float miL = m_i * LOG2E;
  float dacc = 0.f;
  f32x4 acc[4][4] = {};
  int psP = (jt >> 1) ^ ((i_loc >> 1) & 3);
  ushort* pdst = Pt + i_loc * 32 + psP * 8 + (jt & 1) * 4;
  const int* mrow = mask + (i0 + i_loc) * 8192 + jt * 4;

  // stage B tile (32 KB) for iteration `it` into buffer b
#define STAGE_B(b, it_)                                                           \
  {                                                                               \
    int k0_ = kb + (it_) * 32;                                                    \
    ushort* bb_ = &Bt[b][0];                                                      \
    _Pragma("unroll") for (int c = 0; c < 4; ++c) {                               \
      int u_ = c * 512 + t; int rr_ = u_ >> 2, p_ = u_ & 3;                       \
      int sg_ = p_ ^ ((rr_ >> 1) & 3);                                            \
      load_lds16(WhmT + rr_ * 8192 + k0_ + sg_ * 8, bb_ + (c * 512 + (t & ~63)) * 8); \
    }                                                                             \
  }

  // prologue: stage it=0, prefetch regs for it=0
  STAGE_B(0, 0);
  int4 mk = *(const int4*)(mrow + kb);
  float4 smv = *(const float4*)(s_m + kb + jt * 4);

  for (int it = 0; it < 64; ++it) {
    int cur = it & 1;
    // ---- P phase (registers prefetched one iteration ago) ----
    float z0 = sn + smv.x, z1 = sn + smv.y, z2 = sn + smv.z, z3 = sn + smv.w;
    float e0 = (z0 > 0.f ? z0 : 0.2f * z0) * LOG2E - miL;
    float e1 = (z1 > 0.f ? z1 : 0.2f * z1) * LOG2E - miL;
    float e2 = (z2 > 0.f ? z2 : 0.2f * z2) * LOG2E - miL;
    float e3 = (z3 > 0.f ? z3 : 0.2f * z3) * LOG2E - miL;
    float p0 = mk.x > 0 ? exp2f(e0) : 0.f;
    float p1 = mk.y > 0 ? exp2f(e1) : 0.f;
    float p2 = mk.z > 0 ? exp2f(e2) : 0.f;
    float p3 = mk.w > 0 ? exp2f(e3) : 0.f;
    ushort4 pv;
    pv.x = f2bf(p0); pv.y = f2bf(p1); pv.z = f2bf(p2); pv.w = f2bf(p3);
    dacc += bf2f(pv.x) + bf2f(pv.y) + bf2f(pv.z) + bf2f(pv.w);
    *(ushort4*)pdst = pv;
    // ---- drain: only B(cur) (issued a full iteration ago) is in flight ----
    asm volatile("s_waitcnt vmcnt(0) lgkmcnt(0)" ::: "memory");
    __builtin_amdgcn_s_barrier();            // barrier1: B(cur)+P visible
    // ---- issue next iteration's loads; they fly across barrier2 ----
    if (it < 63) {
      STAGE_B(cur ^ 1, it + 1);
      mk  = *(const int4*)(mrow + kb + (it + 1) * 32);
      smv = *(const float4*)(s_m + kb + (it + 1) * 32 + jt * 4);
    }
    __builtin_amdgcn_sched_barrier(0);
    // ---- MFMA phase on Bt[cur], Pt ----
    bf16x8 af[4], bfr[4];
#pragma unroll
    for (int m = 0; m < 4; ++m) {
      int rr2 = m * 16 + (l & 15);
      int q = (l >> 4) ^ ((rr2 >> 1) & 3);
      af[m] = *(const bf16x8*)(Pt + rr2 * 32 + q * 8);
    }
#pragma unroll
    for (int n = 0; n < 4; ++n) {
      int rb2 = w * 64 + n * 16 + (l & 15);
      int q = (l >> 4) ^ ((rb2 >> 1) & 3);
      bfr[n] = *(const bf16x8*)(&Bt[cur][0] + rb2 * 32 + q * 8);
    }
#pragma unroll
    for (int m = 0; m < 4; ++m)
#pragma unroll
      for (int n = 0; n < 4; ++n)
        acc[m][n] = __builtin_amdgcn_mfma_f32_16x16x32_bf16(af[m], bfr[n], acc[m][n], 0, 0, 0);
    __builtin_amdgcn_s_barrier();            // barrier2: frag reads done
  }
  // denominator: 8 threads per row, all in one wave
  dacc += __shfl_xor(dacc, 4, 64);
  dacc += __shfl_xor(dacc, 2, 64);
  dacc += __shfl_xor(dacc, 1, 64);
  if ((t & 7) == 0) den[s * 4096 + i0 + i_loc] = dacc;
  // partial numerator write (f32)
#pragma unroll
  for (int m = 0; m < 4; ++m)
#pragma unroll
    for (int n = 0; n < 4; ++n) {
      int i = i0 + m * 16 + (l >> 4) * 4;
      int f = w * 64 + n * 16 + (l & 15);
      float* dst = num + (s * 4096 + i) * 512 + f;
      dst[0]       = acc[m][n][0];
      dst[512]     = acc[m][n][1];
      dst[2 * 512] = acc[m][n][2];
      dst[3 * 512] = acc[m][n][3];
    }
}

// out[i][f] = sum_s num[s][i][f] / sum_s den[s][i]
__global__ void reduce_out(const float* __restrict__ num, const float* __restrict__ den,
                           float* __restrict__ out) {
  int idx = blockIdx.x * 256 + threadIdx.x;  // 524288 threads
  int i = idx >> 7, f4 = (idx & 127) * 4;
  float4 a = *(const float4*)(num + (size_t)(0 * 4096 + i) * 512 + f4);
  float4 b = *(const float4*)(num + (size_t)(1 * 4096 + i) * 512 + f4);
  float4 c = *(const float4*)(num + (size_t)(2 * 4096 + i) * 512 + f4);
  float4 d = *(const float4*)(num + (size_t)(3 * 4096 + i) * 512 + f4);
  float dn = den[i] + den[4096 + i] + den[2 * 4096 + i] + den[3 * 4096 + i];
  float inv = 1.f / dn;
  float4 o;
  o.x = (a.x + b.x + c.x + d.x) * inv;
  o.y = (a.y + b.y + c.y + d.y) * inv;
  o.z = (a.z + b.z + c.z + d.z) * inv;
  o.w = (a.w + b.w + c.w + d.w) * inv;
  *(float4*)(out + (size_t)i * 512 + f4) = o;
}

extern "C" void kernel_launch(void* const* d_in, const int* in_sizes, int n_in,
                              void* d_out, int out_size, void* d_ws, size_t ws_size,
                              hipStream_t stream) {
  const float* node   = (const float*)d_in[0];
  const float* neigh  = (const float*)d_in[1];
  const float* weight = (const float*)d_in[2];
  const float* att    = (const float*)d_in[3];
  const int*   mask   = (const int*)d_in[4];
  float* out = (float*)d_out;

  char* ws = (char*)d_ws;
  float* w_a1 = (float*)ws;            // 512
  float* w_a2 = w_a1 + 512;            // 512
  float* s_n  = w_a2 + 512;            // 4096
  float* s_m  = s_n + 4096;            // 8192
  float* smax = s_m + 8192;            // 1
  ushort* neigh_bf = (ushort*)(ws + 64 * 1024);    // 8 MB
  ushort* wT_bf    = neigh_bf + 8192 * 512;        // 0.5 MB
  ushort* WhmT     = wT_bf + 512 * 512;            // 8 MB
  float*  num      = (float*)(WhmT + 512 * 8192);  // 32 MB
  float*  den      = num + 4 * 4096 * 512;         // 64 KB

  rowdot<<<128, 256, 0, stream>>>(weight, att, w_a1);
  rowdot<<<128, 256, 0, stream>>>(weight, att + 512, w_a2);
  rowdot<<<1024, 256, 0, stream>>>(node, w_a1, s_n);
  rowdot<<<2048, 256, 0, stream>>>(neigh, w_a2, s_m);
  reduce_max<<<1, 256, 0, stream>>>(s_m, smax);
  cvt4_bf16<<<4096, 256, 0, stream>>>(neigh, neigh_bf);
  transpose_w<<<256, 256, 0, stream>>>(weight, wT_bf);
  gemm_whmT<<<256, 256, 0, stream>>>(neigh_bf, wT_bf, WhmT);
  attn_main<<<256, 512, 0, stream>>>(WhmT, mask, s_n, s_m, smax, num, den);
  reduce_out<<<2048, 256, 0, stream>>>(num, den, out);
}